// Round 4
// baseline (39.548 us; speedup 1.0000x reference)
//
#include <hip/hip_runtime.h>
#include <hip/hip_bf16.h>
#include <float.h>

#define N 8192
#define D 128
#define WAVES 8
#define BM 256                       // rows per block: 8 waves x 32
#define BN 64                        // cols per LDS tile
#define GY 16                        // col-chunks (grid.y)
#define COLS_PER_BLOCK (N / GY)      // 512
#define TILES (COLS_PER_BLOCK / BN)  // 8
#define NPART GY
#define LOSS_BLOCKS (N / 256)        // 32

typedef unsigned short u16;
typedef unsigned int u32;
typedef __attribute__((ext_vector_type(8))) short bf16x8;
typedef __attribute__((ext_vector_type(4))) float f32x4;

typedef const __attribute__((address_space(1))) u32 glb_u32;
typedef __attribute__((address_space(3))) u32 lds_u32;

__device__ inline u16 f32_to_bf16_rtne(float f) {
  union { float f; unsigned int u; } c; c.f = f;
  unsigned int u = c.u;
  u += 0x7FFFu + ((u >> 16) & 1u);
  return (u16)(u >> 16);
}

// ---------------- kernel 1: f32 -> bf16 convert ----------------
__global__ __launch_bounds__(256) void convert_kernel(const float* __restrict__ P,
                                                      u16* __restrict__ Pb) {
  int i = blockIdx.x * 256 + threadIdx.x;
  float4 v = reinterpret_cast<const float4*>(P)[i];
  uint2 o;
  o.x = (unsigned)f32_to_bf16_rtne(v.x) | ((unsigned)f32_to_bf16_rtne(v.y) << 16);
  o.y = (unsigned)f32_to_bf16_rtne(v.z) | ((unsigned)f32_to_bf16_rtne(v.w) << 16);
  reinterpret_cast<uint2*>(Pb)[i] = o;
}

// ---------------- kernel 2 body: 3-deep pipelined fused sim + min/max ----------
// 8 waves x 32 rows. Swizzle (validated r2/r3): LDS_off(c,o) = c*256 + (o^((c&15)<<4)),
// applied on the global SOURCE at stage time and on the ds_read address (rule 21).
template <bool DIAG>
__device__ __forceinline__ void pipeline(const char* __restrict__ pbb,
                                         const int* __restrict__ y,
                                         float* __restrict__ pmin,
                                         float* __restrict__ pmax,
                                         char* ldsB, int* ldsY,
                                         int R0, int C0, int slot) {
  const int tid  = threadIdx.x;
  const int w    = tid >> 6;         // 0..7
  const int lane = tid & 63;
  const int c15  = lane & 15;
  const int g    = lane >> 4;

  // y for the block's 512 cols: wave w loads 64 ints
  __builtin_amdgcn_global_load_lds((glb_u32*)(y + C0 + w * 64 + lane),
                                   (lds_u32*)(ldsY + w * 64), 4, 0, 0);

  // stage tile t: 16KB, 2 glds x 1KB per wave (uniform count for vmcnt math)
  auto STAGE = [&](int buf, int t) {
    const char* gb = pbb + (size_t)(C0 + t * BN) * 256;
    char* base = ldsB + buf * (BN * 256);
#pragma unroll
    for (int j = 0; j < 2; ++j) {
      const int L = ((w * 2 + j) * 64 + lane) * 16;    // linear LDS byte
      const int c = L >> 8;
      const int o = L & 255;
      const int src = c * 256 + (o ^ ((c & 15) << 4)); // inverse-swizzled source
      __builtin_amdgcn_global_load_lds((glb_u32*)(gb + src),
                                       (lds_u32*)(base + (w * 2 + j) * 1024), 16, 0, 0);
    }
  };

  STAGE(0, 0);
  STAGE(1, 1);

  const int rowbase = R0 + w * 32 + g * 4;   // + rg*16 + r

  // A fragments: 2 rowgroups x 16 rows, K=128 (32 VGPRs)
  bf16x8 afrag[2][4];
#pragma unroll
  for (int rg = 0; rg < 2; ++rg) {
    const char* ap = pbb + (size_t)(R0 + w * 32 + rg * 16 + c15) * 256 + g * 16;
#pragma unroll
    for (int kk = 0; kk < 4; ++kk)
      afrag[rg][kk] = *reinterpret_cast<const bf16x8*>(ap + kk * 64);
  }

  int yrow[2][4];
#pragma unroll
  for (int rg = 0; rg < 2; ++rg)
#pragma unroll
    for (int r = 0; r < 4; ++r)
      yrow[rg][r] = y[rowbase + rg * 16 + r];

  float mins[2][4], maxd[2][4];
#pragma unroll
  for (int rg = 0; rg < 2; ++rg)
#pragma unroll
    for (int r = 0; r < 4; ++r) { mins[rg][r] = FLT_MAX; maxd[rg][r] = -FLT_MAX; }

#pragma unroll 1
  for (int t = 0; t < TILES; ++t) {
    // counted vmcnt: stage(t) drained (FIFO), stage(t+1)'s 2 loads stay in flight
    if (t + 1 < TILES) asm volatile("s_waitcnt vmcnt(2)" ::: "memory");
    else               asm volatile("s_waitcnt vmcnt(0)" ::: "memory");
    __builtin_amdgcn_s_barrier();          // all waves' stage(t) landed;
                                           // buf[(t+2)%3] free (was read in t-1)
    if (t + 2 < TILES) STAGE((t + 2) % 3, t + 2);

    const char* Bb = ldsB + (t % 3) * (BN * 256);
#pragma unroll
    for (int s = 0; s < 4; ++s) {
      const int c = s * 16 + c15;
      bf16x8 bf[4];
#pragma unroll
      for (int kk = 0; kk < 4; ++kk) {
        const int off = c * 256 + (((g * 16) | (kk * 64)) ^ (c15 << 4));
        bf[kk] = *reinterpret_cast<const bf16x8*>(Bb + off);
      }
      f32x4 acc0 = {0.f, 0.f, 0.f, 0.f}, acc1 = {0.f, 0.f, 0.f, 0.f};
      __builtin_amdgcn_s_setprio(1);
#pragma unroll
      for (int kk = 0; kk < 4; ++kk) {
        acc0 = __builtin_amdgcn_mfma_f32_16x16x32_bf16(afrag[0][kk], bf[kk], acc0, 0, 0, 0);
        acc1 = __builtin_amdgcn_mfma_f32_16x16x32_bf16(afrag[1][kk], bf[kk], acc1, 0, 0, 0);
      }
      __builtin_amdgcn_s_setprio(0);
      const int colB = t * BN + c;
      const int ycol = ldsY[colB];
      const int col  = C0 + colB;
#pragma unroll
      for (int r = 0; r < 4; ++r) {
        {
          const float v = acc0[r];
          const bool same = (ycol == yrow[0][r]);
          bool okmin = same;
          if (DIAG) okmin = same && (col != rowbase + r);
          mins[0][r] = fminf(mins[0][r], okmin ? v : FLT_MAX);
          maxd[0][r] = fmaxf(maxd[0][r], same ? -FLT_MAX : v);
        }
        {
          const float v = acc1[r];
          const bool same = (ycol == yrow[1][r]);
          bool okmin = same;
          if (DIAG) okmin = same && (col != rowbase + 16 + r);
          mins[1][r] = fminf(mins[1][r], okmin ? v : FLT_MAX);
          maxd[1][r] = fmaxf(maxd[1][r], same ? -FLT_MAX : v);
        }
      }
    }
  }

  // butterfly over the 16 col-lanes (bits 0-3; stays within g-group)
#pragma unroll
  for (int off = 1; off < 16; off <<= 1)
#pragma unroll
    for (int rg = 0; rg < 2; ++rg)
#pragma unroll
      for (int r = 0; r < 4; ++r) {
        mins[rg][r] = fminf(mins[rg][r], __shfl_xor(mins[rg][r], off, 64));
        maxd[rg][r] = fmaxf(maxd[rg][r], __shfl_xor(maxd[rg][r], off, 64));
      }

  if (c15 == 0) {
#pragma unroll
    for (int rg = 0; rg < 2; ++rg)
#pragma unroll
      for (int r = 0; r < 4; ++r) {
        pmin[(size_t)slot * N + rowbase + rg * 16 + r] = mins[rg][r];
        pmax[(size_t)slot * N + rowbase + rg * 16 + r] = maxd[rg][r];
      }
  }
}

__global__ __launch_bounds__(512, 4) void margin_main(const u16* __restrict__ Pb,
                                                      const int* __restrict__ y,
                                                      float* __restrict__ pmin,
                                                      float* __restrict__ pmax) {
  __shared__ __align__(16) char ldsB[3][BN * 256];   // 48 KB, 3-deep
  __shared__ int ldsY[COLS_PER_BLOCK];               // 2 KB
  const int R0 = blockIdx.x * BM;
  const int C0 = blockIdx.y * COLS_PER_BLOCK;
  if ((unsigned)(R0 - C0) < (unsigned)COLS_PER_BLOCK)
    pipeline<true>((const char*)Pb, y, pmin, pmax, &ldsB[0][0], ldsY, R0, C0, blockIdx.y);
  else
    pipeline<false>((const char*)Pb, y, pmin, pmax, &ldsB[0][0], ldsY, R0, C0, blockIdx.y);
}

// ---------------- kernel 3: combine partials, hinge, block sums ----------------
__global__ __launch_bounds__(256) void loss_kernel(const float* __restrict__ pmin,
                                                   const float* __restrict__ pmax,
                                                   float* __restrict__ blockSums) {
  const int row = blockIdx.x * 256 + threadIdx.x;
  float mn = FLT_MAX, mx = -FLT_MAX;
#pragma unroll
  for (int s = 0; s < NPART; ++s) {            // slot-major: coalesced
    mn = fminf(mn, pmin[(size_t)s * N + row]);
    mx = fmaxf(mx, pmax[(size_t)s * N + row]);
  }
  if (mn == FLT_MAX)  mn = 0.f;
  if (mx == -FLT_MAX) mx = 0.f;
  float loss = fmaxf(0.f, mn + mx + 1.0f);     // TAU = 1.0

#pragma unroll
  for (int off = 32; off >= 1; off >>= 1)
    loss += __shfl_down(loss, off, 64);
  __shared__ float wsum[4];
  if ((threadIdx.x & 63) == 0) wsum[threadIdx.x >> 6] = loss;
  __syncthreads();
  if (threadIdx.x == 0)
    blockSums[blockIdx.x] = wsum[0] + wsum[1] + wsum[2] + wsum[3];
}

// ---------------- kernel 4: final mean ----------------
__global__ __launch_bounds__(64) void finalize_kernel(const float* __restrict__ blockSums,
                                                      float* __restrict__ out) {
  float v = (threadIdx.x < LOSS_BLOCKS) ? blockSums[threadIdx.x] : 0.f;
#pragma unroll
  for (int off = 32; off >= 1; off >>= 1)
    v += __shfl_down(v, off, 64);
  if (threadIdx.x == 0) out[0] = v / (float)N;
}

extern "C" void kernel_launch(void* const* d_in, const int* in_sizes, int n_in,
                              void* d_out, int out_size, void* d_ws, size_t ws_size,
                              hipStream_t stream) {
  const float* P = (const float*)d_in[0];
  const int*   y = (const int*)d_in[1];
  float* out = (float*)d_out;

  u16*   Pb        = (u16*)d_ws;
  float* pmin      = (float*)((char*)d_ws + (size_t)N * D * sizeof(u16));
  float* pmax      = pmin + (size_t)N * NPART;
  float* blockSums = pmax + (size_t)N * NPART;

  convert_kernel<<<dim3(N * D / 4 / 256), 256, 0, stream>>>(P, Pb);
  margin_main<<<dim3(N / BM, GY), 512, 0, stream>>>(Pb, y, pmin, pmax);
  loss_kernel<<<dim3(LOSS_BLOCKS), 256, 0, stream>>>(pmin, pmax, blockSums);
  finalize_kernel<<<1, 64, 0, stream>>>(blockSums, out);
}